// Round 13
// baseline (224.572 us; speedup 1.0000x reference)
//
#include <hip/hip_runtime.h>
#include <hip/hip_bf16.h>
#include <math.h>

#define N 8192
#define D 1024
#define BM 256
#define BK 64
#define NQUART 64                       // 16 tiles (ti=31, tj=0..15) x 4 quadrants
#define NFULL 512                       // 528 - 16 quartered tiles
#define ITERS 8                         // full path: 16 K-tiles / 2 per iter

typedef __bf16 bf16_t;
typedef bf16_t bf16x4 __attribute__((ext_vector_type(4)));
typedef bf16_t bf16x8 __attribute__((ext_vector_type(8)));
typedef float f32x4 __attribute__((ext_vector_type(4)));

// ---------------------------------------------------------------------------
// Kernel 1: L2-normalize each row, cast to bf16. Wave-per-row. Also zeroes
// sumExp/posSum (replaces the memset dispatch).
// ---------------------------------------------------------------------------
__global__ __launch_bounds__(256) void norm_cast(const float* __restrict__ in,
                                                 bf16_t* __restrict__ out,
                                                 float* __restrict__ sumExp,
                                                 float* __restrict__ posSum) {
    const int wave = threadIdx.x >> 6, lane = threadIdx.x & 63;
    const int row  = blockIdx.x * 4 + wave;
    const float4* src = (const float4*)(in + (size_t)row * D);
    float4 v[4];
    float ss = 0.f;
    #pragma unroll
    for (int i = 0; i < 4; ++i) {
        v[i] = src[lane + 64 * i];
        ss += v[i].x * v[i].x + v[i].y * v[i].y + v[i].z * v[i].z + v[i].w * v[i].w;
    }
    #pragma unroll
    for (int off = 32; off >= 1; off >>= 1) ss += __shfl_xor(ss, off, 64);
    const float scale = 1.0f / fmaxf(sqrtf(ss), 1e-12f);
    bf16x4* dst = (bf16x4*)(out + (size_t)row * D);
    #pragma unroll
    for (int i = 0; i < 4; ++i) {
        bf16x4 o;
        o[0] = (bf16_t)(v[i].x * scale);
        o[1] = (bf16_t)(v[i].y * scale);
        o[2] = (bf16_t)(v[i].z * scale);
        o[3] = (bf16_t)(v[i].w * scale);
        dst[lane + 64 * i] = o;
    }
    if (lane == 0) { sumExp[row] = 0.f; posSum[row] = 0.f; }
}

#define PHASE_MID() do {                                                             \
    __builtin_amdgcn_s_barrier();                                                    \
    asm volatile("s_waitcnt lgkmcnt(0)");                                            \
    __builtin_amdgcn_sched_barrier(0);                                               \
    __builtin_amdgcn_s_setprio(1);                                                   \
} while (0)
#define PHASE_END() do {                                                             \
    __builtin_amdgcn_s_setprio(0);                                                   \
    __builtin_amdgcn_s_barrier();                                                    \
} while (0)

// ---------------------------------------------------------------------------
// Kernel 2a: FULL tiles — R2's verified 256^2 / BK=64 / 8-phase kernel,
// 512 blocks (the 16 ti=31,tj=0..15 tiles are handled by gemm_quart).
// ---------------------------------------------------------------------------
__global__ __launch_bounds__(512, 2) void gemm_full(const bf16_t* __restrict__ E,
                                                    const int* __restrict__ labels,
                                                    float* __restrict__ sumExp,
                                                    float* __restrict__ posSum) {
    __shared__ bf16_t As[2][2][128 * 64];   // 64 KB
    __shared__ bf16_t Bs[2][2][128 * 64];   // 64 KB  (total 131072 B)

    const int tid  = threadIdx.x;
    const int wave = tid >> 6;
    const int lane = tid & 63;
    const int lr   = lane & 15;
    const int q    = lane >> 4;
    const float invT = 1.0f / 0.07f;

    const int su0 = ((0 + q) ^ (lane & 7)) * 16;     // k = 0
    const int su1 = ((4 + q) ^ (lane & 7)) * 16;     // k = 1

    const int f0 = (int)blockIdx.x;
    const int f  = (f0 & 7) * (NFULL / 8) + (f0 >> 3);     // XCD swizzle, 512%8==0
    const int b  = (f < 496) ? f : f + 16;                 // skip quartered tiles

    int ti = (int)((sqrtf(8.0f * (float)b + 1.0f) - 1.0f) * 0.5f);
    while ((ti + 1) * (ti + 2) / 2 <= b) ++ti;
    while (ti * (ti + 1) / 2 > b) --ti;
    const int tj = b - ti * (ti + 1) / 2;
    const bool isDiag = (ti == tj);

    const int wm   = wave >> 2;     // 0..1 : row half
    const int wn   = wave & 3;      // 0..3 : 64-col strip
    const int rowStart = ti * BM;
    const int colStart = tj * BM;

    f32x4 acc[8][4];
    #pragma unroll
    for (int m = 0; m < 8; ++m)
        #pragma unroll
        for (int n = 0; n < 4; ++n) acc[m][n] = {0.f, 0.f, 0.f, 0.f};

    const int r0  = tid >> 3;                    // 0..63 (second load adds 64 rows)
    const int lu0 = (tid & 7) ^ (r0 & 7);
    const char* gA = (const char*)(E + (size_t)rowStart * D) + (size_t)r0 * (D * 2) + lu0 * 16;
    const char* gB = (const char*)(E + (size_t)colStart * D) + (size_t)r0 * (D * 2) + lu0 * 16;

    #define STAGE_A(buf, h, kb) do {                                                     \
        const char* g0_ = gA + (size_t)(h) * (128 * 2048) + (kb);                        \
        char* l0_ = (char*)&As[buf][h][0] + wave * 1024;                                 \
        __builtin_amdgcn_global_load_lds((const __attribute__((address_space(1))) void*)g0_, \
            (__attribute__((address_space(3))) void*)l0_, 16, 0, 0);                     \
        __builtin_amdgcn_global_load_lds(                                                \
            (const __attribute__((address_space(1))) void*)(g0_ + 64 * 2048),            \
            (__attribute__((address_space(3))) void*)(l0_ + 8192), 16, 0, 0);            \
    } while (0)
    #define STAGE_B(buf, h, kb) do {                                                     \
        const char* g0_ = gB + (size_t)(h) * (128 * 2048) + (kb);                        \
        char* l0_ = (char*)&Bs[buf][h][0] + wave * 1024;                                 \
        __builtin_amdgcn_global_load_lds((const __attribute__((address_space(1))) void*)g0_, \
            (__attribute__((address_space(3))) void*)l0_, 16, 0, 0);                     \
        __builtin_amdgcn_global_load_lds(                                                \
            (const __attribute__((address_space(1))) void*)(g0_ + 64 * 2048),            \
            (__attribute__((address_space(3))) void*)(l0_ + 8192), 16, 0, 0);            \
    } while (0)

    const char* rA0 = (const char*)&As[0][wm][0] + lr * 128;
    const char* rA1 = (const char*)&As[1][wm][0] + lr * 128;
    const char* rB0 = (const char*)&Bs[0][wn >> 1][0] + (wn & 1) * 8192 + lr * 128;
    const char* rB1 = (const char*)&Bs[1][wn >> 1][0] + (wn & 1) * 8192 + lr * 128;

    #define LD_A4(DST, RBASE, MOFFB, SU) do {                                            \
        _Pragma("unroll")                                                                \
        for (int m_ = 0; m_ < 4; ++m_)                                                   \
            DST[m_] = *(const bf16x8*)((RBASE) + (MOFFB) + m_ * 2048 + (SU));            \
    } while (0)
    #define LD_B4(DST, RBASE, SU) do {                                                   \
        _Pragma("unroll")                                                                \
        for (int n_ = 0; n_ < 4; ++n_)                                                   \
            DST[n_] = *(const bf16x8*)((RBASE) + n_ * 2048 + (SU));                      \
    } while (0)
    #define MFMA_QUAD(AF, BF, MO) do {                                                   \
        _Pragma("unroll")                                                                \
        for (int m_ = 0; m_ < 4; ++m_) {                                                 \
            _Pragma("unroll")                                                            \
            for (int n_ = 0; n_ < 4; ++n_)                                               \
                acc[(MO) + m_][n_] = __builtin_amdgcn_mfma_f32_16x16x32_bf16(            \
                    AF[m_], BF[n_], acc[(MO) + m_][n_], 0, 0, 0);                        \
        }                                                                                \
    } while (0)

    bf16x8 a0[4], a1[4], bq0[4], bq1[4];

    STAGE_B(0, 0, 0);  STAGE_B(0, 1, 0);
    STAGE_A(0, 0, 0);  STAGE_A(0, 1, 0);
    STAGE_B(1, 0, 128); STAGE_B(1, 1, 128);
    asm volatile("s_waitcnt vmcnt(4)" ::: "memory");
    __builtin_amdgcn_sched_barrier(0);
    __builtin_amdgcn_s_barrier();

    #pragma unroll 1
    for (int it = 0; it < ITERS; ++it) {
        const bool lastIt = (it == ITERS - 1);
        const int kb1 = (2 * it + 1) * 128;
        const int kb2 = (2 * it + 2) * 128;
        const int kb3 = (2 * it + 3) * 128;

        LD_A4(a0, rA0, 0, su0);
        LD_B4(bq0, rB0, su0);
        STAGE_A(1, 0, kb1);
        PHASE_MID();
        MFMA_QUAD(a0, bq0, 0);
        PHASE_END();

        LD_A4(a1, rA0, 0, su1);
        LD_B4(bq1, rB0, su1);
        STAGE_A(1, 1, kb1);
        PHASE_MID();
        MFMA_QUAD(a1, bq1, 0);
        PHASE_END();

        LD_A4(a0, rA0, 8192, su0);
        if (!lastIt) STAGE_B(0, 0, kb2);
        PHASE_MID();
        MFMA_QUAD(a0, bq0, 4);
        PHASE_END();

        LD_A4(a1, rA0, 8192, su1);
        if (!lastIt) {
            STAGE_B(0, 1, kb2);
            asm volatile("s_waitcnt vmcnt(4)" ::: "memory");
        } else {
            asm volatile("s_waitcnt vmcnt(0)" ::: "memory");
        }
        __builtin_amdgcn_sched_barrier(0);
        PHASE_MID();
        MFMA_QUAD(a1, bq1, 4);
        PHASE_END();

        LD_A4(a0, rA1, 0, su0);
        LD_B4(bq0, rB1, su0);
        if (!lastIt) STAGE_A(0, 0, kb2);
        PHASE_MID();
        MFMA_QUAD(a0, bq0, 0);
        PHASE_END();

        LD_A4(a1, rA1, 0, su1);
        LD_B4(bq1, rB1, su1);
        if (!lastIt) STAGE_A(0, 1, kb2);
        PHASE_MID();
        MFMA_QUAD(a1, bq1, 0);
        PHASE_END();

        LD_A4(a0, rA1, 8192, su0);
        if (!lastIt) STAGE_B(1, 0, kb3);
        PHASE_MID();
        MFMA_QUAD(a0, bq0, 4);
        PHASE_END();

        LD_A4(a1, rA1, 8192, su1);
        if (!lastIt) {
            STAGE_B(1, 1, kb3);
            asm volatile("s_waitcnt vmcnt(4)" ::: "memory");
            __builtin_amdgcn_sched_barrier(0);
        }
        PHASE_MID();
        MFMA_QUAD(a1, bq1, 4);
        PHASE_END();
    }

    int lc[4];
    #pragma unroll
    for (int n = 0; n < 4; ++n)
        lc[n] = labels[colStart + wn * 64 + n * 16 + lr];

    float colAll[4] = {0.f, 0.f, 0.f, 0.f};
    float colPos[4] = {0.f, 0.f, 0.f, 0.f};
    #pragma unroll
    for (int m = 0; m < 8; ++m) {
        #pragma unroll
        for (int e = 0; e < 4; ++e) {
            const int rloc = wm * 128 + m * 16 + q * 4 + e;
            const int gi   = rowStart + rloc;
            const int li   = labels[gi];
            float s_all = 0.f, s_pos = 0.f;
            #pragma unroll
            for (int n = 0; n < 4; ++n) {
                const int cloc = wn * 64 + n * 16 + lr;
                const int gj   = colStart + cloc;
                const float v  = __expf(acc[m][n][e] * invT);
                const bool same = (lc[n] == li);
                s_all += v;
                if (same && gi != gj) s_pos += v;
                if (!isDiag) {
                    colAll[n] += v;
                    if (same) colPos[n] += v;
                }
            }
            #pragma unroll
            for (int off = 1; off < 16; off <<= 1) {
                s_all += __shfl_xor(s_all, off, 64);
                s_pos += __shfl_xor(s_pos, off, 64);
            }
            if (lr == 0) {
                atomicAdd(&sumExp[gi], s_all);
                atomicAdd(&posSum[gi], s_pos);
            }
        }
    }
    if (!isDiag) {
        #pragma unroll
        for (int n = 0; n < 4; ++n) {
            float a = colAll[n], p = colPos[n];
            a += __shfl_xor(a, 16, 64);  a += __shfl_xor(a, 32, 64);
            p += __shfl_xor(p, 16, 64);  p += __shfl_xor(p, 32, 64);
            if (q == 0) {
                const int gj = colStart + wn * 64 + n * 16 + lr;
                atomicAdd(&sumExp[gj], a);
                atomicAdd(&posSum[gj], p);
            }
        }
    }
}

// ---------------------------------------------------------------------------
// Kernel 2b: QUARTER tiles (64 blocks): 128x128, BK=64, 4-slot LDS ring
// (4 x 16 KB x 2 = 128 KiB), single phase per K-step, counted vmcnt(8)
// (2 K-tiles always in flight). 128-B LDS rows -> R2's proven conflict-free
// swizzle (identical formulas). All quarters strictly below the diagonal.
// ---------------------------------------------------------------------------
__global__ __launch_bounds__(512, 2) void gemm_quart(const bf16_t* __restrict__ E,
                                                     const int* __restrict__ labels,
                                                     float* __restrict__ sumExp,
                                                     float* __restrict__ posSum) {
    __shared__ bf16_t As[4][128 * 64];   // 4 x 16 KB ring
    __shared__ bf16_t Bs[4][128 * 64];   // 4 x 16 KB ring (total 131072 B)

    const int tid  = threadIdx.x;
    const int wave = tid >> 6;
    const int lane = tid & 63;
    const int lr   = lane & 15;
    const int q    = lane >> 4;
    const float invT = 1.0f / 0.07f;

    const int qb = (int)blockIdx.x;             // 0..63
    const int p  = qb >> 2, qd = qb & 3;
    const int rowStart = 31 * BM + (qd >> 1) * 128;
    const int colStart = p * BM + (qd & 1) * 128;
    const int wm2 = wave >> 2;      // 0..1 : 64-row half
    const int wn2 = wave & 3;       // 0..3 : 32-col strip

    f32x4 acc[4][2];
    #pragma unroll
    for (int m = 0; m < 4; ++m) { acc[m][0] = {0,0,0,0}; acc[m][1] = {0,0,0,0}; }

    // staging: per gload 512 thr x 16B = 8 KB = rows 0..63 x 128 B.
    const int r0  = tid >> 3;                    // 0..63
    const int lu0 = (tid & 7) ^ (r0 & 7);
    const char* gA = (const char*)(E + (size_t)rowStart * D) + (size_t)r0 * (D * 2) + lu0 * 16;
    const char* gB = (const char*)(E + (size_t)colStart * D) + (size_t)r0 * (D * 2) + lu0 * 16;

    // stage K-tile into ring slot: A rows 0-63, 64-127; B rows 0-63, 64-127.
    #define QST(slot, kb) do {                                                           \
        const char* ga_ = gA + (kb);                                                     \
        const char* gb_ = gB + (kb);                                                     \
        char* la_ = (char*)&As[slot][0] + wave * 1024;                                   \
        char* lb_ = (char*)&Bs[slot][0] + wave * 1024;                                   \
        __builtin_amdgcn_global_load_lds((const __attribute__((address_space(1))) void*)ga_, \
            (__attribute__((address_space(3))) void*)la_, 16, 0, 0);                     \
        __builtin_amdgcn_global_load_lds(                                                \
            (const __attribute__((address_space(1))) void*)(ga_ + 64 * 2048),            \
            (__attribute__((address_space(3))) void*)(la_ + 8192), 16, 0, 0);            \
        __builtin_amdgcn_global_load_lds((const __attribute__((address_space(1))) void*)gb_, \
            (__attribute__((address_space(3))) void*)lb_, 16, 0, 0);                     \
        __builtin_amdgcn_global_load_lds(                                                \
            (const __attribute__((address_space(1))) void*)(gb_ + 64 * 2048),            \
            (__attribute__((address_space(3))) void*)(lb_ + 8192), 16, 0, 0);            \
    } while (0)

    const int su0 = ((0 + q) ^ (lane & 7)) * 16;
    const int su1 = ((4 + q) ^ (lane & 7)) * 16;

    // prologue: stage T0,T1,T2 (12 loads); vmcnt(8) -> T0 landed.
    QST(0, 0);
    QST(1, 128);
    QST(2, 256);
    asm volatile("s_waitcnt vmcnt(8)" ::: "memory");
    __builtin_amdgcn_sched_barrier(0);
    __builtin_amdgcn_s_barrier();

    #pragma unroll 1
    for (int s = 0; s < 16; ++s) {
        const int slot = s & 3;
        if (s <= 12) QST((s + 3) & 3, (s + 3) * 128);   // WAR ok: slot read in step s-1
        const char* aB = (const char*)&As[slot][0] + (wm2 * 64 + lr) * 128;
        const char* bB = (const char*)&Bs[slot][0] + (wn2 * 32 + lr) * 128;
        bf16x8 qa0[4], qa1[4], qb0v[2], qb1v[2];
        #pragma unroll
        for (int m_ = 0; m_ < 4; ++m_) {
            qa0[m_] = *(const bf16x8*)(aB + m_ * 2048 + su0);
            qa1[m_] = *(const bf16x8*)(aB + m_ * 2048 + su1);
        }
        qb0v[0] = *(const bf16x8*)(bB + su0);
        qb0v[1] = *(const bf16x8*)(bB + 2048 + su0);
        qb1v[0] = *(const bf16x8*)(bB + su1);
        qb1v[1] = *(const bf16x8*)(bB + 2048 + su1);
        asm volatile("s_waitcnt lgkmcnt(0)");
        __builtin_amdgcn_sched_barrier(0);
        __builtin_amdgcn_s_setprio(1);
        #pragma unroll
        for (int m_ = 0; m_ < 4; ++m_) {
            #pragma unroll
            for (int n_ = 0; n_ < 2; ++n_)
                acc[m_][n_] = __builtin_amdgcn_mfma_f32_16x16x32_bf16(
                    qa0[m_], qb0v[n_], acc[m_][n_], 0, 0, 0);
        }
        #pragma unroll
        for (int m_ = 0; m_ < 4; ++m_) {
            #pragma unroll
            for (int n_ = 0; n_ < 2; ++n_)
                acc[m_][n_] = __builtin_amdgcn_mfma_f32_16x16x32_bf16(
                    qa1[m_], qb1v[n_], acc[m_][n_], 0, 0, 0);
        }
        __builtin_amdgcn_s_setprio(0);
        // counted wait: keep 2 K-tiles in flight; drain the tile needed next.
        if (s <= 12)      asm volatile("s_waitcnt vmcnt(8)" ::: "memory");
        else if (s == 13) asm volatile("s_waitcnt vmcnt(4)" ::: "memory");
        else              asm volatile("s_waitcnt vmcnt(0)" ::: "memory");
        __builtin_amdgcn_sched_barrier(0);
        __builtin_amdgcn_s_barrier();
    }

    // epilogue (always off-diagonal, gi != gj guaranteed)
    int lc[2];
    lc[0] = labels[colStart + wn2 * 32 + lr];
    lc[1] = labels[colStart + wn2 * 32 + 16 + lr];
    float colAll[2] = {0.f, 0.f}, colPos[2] = {0.f, 0.f};
    #pragma unroll
    for (int m = 0; m < 4; ++m) {
        #pragma unroll
        for (int e = 0; e < 4; ++e) {
            const int gi = rowStart + wm2 * 64 + m * 16 + q * 4 + e;
            const int li = labels[gi];
            float s_all = 0.f, s_pos = 0.f;
            #pragma unroll
            for (int n = 0; n < 2; ++n) {
                const float v = __expf(acc[m][n][e] * invT);
                const bool same = (lc[n] == li);
                s_all += v;
                if (same) s_pos += v;
                colAll[n] += v;
                if (same) colPos[n] += v;
            }
            #pragma unroll
            for (int off = 1; off < 16; off <<= 1) {
                s_all += __shfl_xor(s_all, off, 64);
                s_pos += __shfl_xor(s_pos, off, 64);
            }
            if (lr == 0) {
                atomicAdd(&sumExp[gi], s_all);
                atomicAdd(&posSum[gi], s_pos);
            }
        }
    }
    #pragma unroll
    for (int n = 0; n < 2; ++n) {
        float a = colAll[n], pp = colPos[n];
        a += __shfl_xor(a, 16, 64);  a += __shfl_xor(a, 32, 64);
        pp += __shfl_xor(pp, 16, 64); pp += __shfl_xor(pp, 32, 64);
        if (q == 0) {
            const int gj = colStart + wn2 * 32 + n * 16 + lr;
            atomicAdd(&sumExp[gj], a);
            atomicAdd(&posSum[gj], pp);
        }
    }
}

// ---------------------------------------------------------------------------
// Kernel 3: loss_i = log(sumExp_i / posSum_i); out = mean(loss).
// ---------------------------------------------------------------------------
__global__ __launch_bounds__(1024) void finalize(const float* __restrict__ sumExp,
                                                 const float* __restrict__ posSum,
                                                 float* __restrict__ out) {
    const int tid = threadIdx.x;
    float s = 0.f;
    #pragma unroll
    for (int i = tid; i < N; i += 1024)
        s += __logf(sumExp[i] / posSum[i]);
    #pragma unroll
    for (int off = 32; off >= 1; off >>= 1) s += __shfl_xor(s, off, 64);
    __shared__ float red[16];
    if ((tid & 63) == 0) red[tid >> 6] = s;
    __syncthreads();
    if (tid == 0) {
        float t = 0.f;
        #pragma unroll
        for (int i = 0; i < 16; ++i) t += red[i];
        out[0] = t / (float)N;
    }
}

extern "C" void kernel_launch(void* const* d_in, const int* in_sizes, int n_in,
                              void* d_out, int out_size, void* d_ws, size_t ws_size,
                              hipStream_t stream) {
    const float* emb    = (const float*)d_in[0];
    const int*   labels = (const int*)d_in[1];
    float* out = (float*)d_out;

    // ws layout: [sumExp: N floats][posSum: N floats][EN: N*D bf16]
    float*  sumExp = (float*)d_ws;
    float*  posSum = sumExp + N;
    bf16_t* EN     = (bf16_t*)((char*)d_ws + (size_t)2 * N * sizeof(float));

    norm_cast<<<N / 4, 256, 0, stream>>>(emb, EN, sumExp, posSum);

    gemm_full<<<NFULL, 512, 0, stream>>>(EN, labels, sumExp, posSum);
    gemm_quart<<<NQUART, 512, 0, stream>>>(EN, labels, sumExp, posSum);

    finalize<<<1, 1024, 0, stream>>>(sumExp, posSum, out);
}

// Round 14
// 219.042 us; speedup vs baseline: 1.0252x; 1.0252x over previous
//
#include <hip/hip_runtime.h>
#include <hip/hip_bf16.h>
#include <math.h>

#define N 8192
#define D 1024
#define BM 256
#define BK 64
#define NQUART 64                       // 16 tiles (ti=31, tj=0..15) x 4 quadrants
#define NFULL 512                       // 528 - 16 quartered tiles
#define NBLK (NFULL + NQUART)           // 576: fulls 0..511, quarters 512..575
#define ITERS 8                         // full path: 16 K-tiles / 2 per iter

typedef __bf16 bf16_t;
typedef bf16_t bf16x4 __attribute__((ext_vector_type(4)));
typedef bf16_t bf16x8 __attribute__((ext_vector_type(8)));
typedef float f32x4 __attribute__((ext_vector_type(4)));

// ---------------------------------------------------------------------------
// Kernel 1: L2-normalize each row, cast to bf16. Wave-per-row. Also zeroes
// sumExp/posSum and the gemm completion counter (visible to gemm via the
// implicit kernel-end release, same as EN itself).
// ---------------------------------------------------------------------------
__global__ __launch_bounds__(256) void norm_cast(const float* __restrict__ in,
                                                 bf16_t* __restrict__ out,
                                                 float* __restrict__ sumExp,
                                                 float* __restrict__ posSum,
                                                 int* __restrict__ cnt) {
    const int wave = threadIdx.x >> 6, lane = threadIdx.x & 63;
    const int row  = blockIdx.x * 4 + wave;
    if (blockIdx.x == 0 && threadIdx.x == 0) *cnt = 0;
    const float4* src = (const float4*)(in + (size_t)row * D);
    float4 v[4];
    float ss = 0.f;
    #pragma unroll
    for (int i = 0; i < 4; ++i) {
        v[i] = src[lane + 64 * i];
        ss += v[i].x * v[i].x + v[i].y * v[i].y + v[i].z * v[i].z + v[i].w * v[i].w;
    }
    #pragma unroll
    for (int off = 32; off >= 1; off >>= 1) ss += __shfl_xor(ss, off, 64);
    const float scale = 1.0f / fmaxf(sqrtf(ss), 1e-12f);
    bf16x4* dst = (bf16x4*)(out + (size_t)row * D);
    #pragma unroll
    for (int i = 0; i < 4; ++i) {
        bf16x4 o;
        o[0] = (bf16_t)(v[i].x * scale);
        o[1] = (bf16_t)(v[i].y * scale);
        o[2] = (bf16_t)(v[i].z * scale);
        o[3] = (bf16_t)(v[i].w * scale);
        dst[lane + 64 * i] = o;
    }
    if (lane == 0) { sumExp[row] = 0.f; posSum[row] = 0.f; }
}

#define PHASE_MID() do {                                                             \
    __builtin_amdgcn_s_barrier();                                                    \
    asm volatile("s_waitcnt lgkmcnt(0)");                                            \
    __builtin_amdgcn_sched_barrier(0);                                               \
    __builtin_amdgcn_s_setprio(1);                                                   \
} while (0)
#define PHASE_END() do {                                                             \
    __builtin_amdgcn_s_setprio(0);                                                   \
    __builtin_amdgcn_s_barrier();                                                    \
} while (0)

// ---------------------------------------------------------------------------
// Kernel 2: fused symmetric  C = E·E^T / T -> exp -> masked row+col sums,
// plus last-finishing-block finalize (NO per-block fences: sums are written
// only by device-scope atomics; __syncthreads' implicit vmcnt drain orders
// them before the done-counter increment; reader uses agent-scope loads).
// Fulls 0..511 = R2's verified 256^2/BK=64/8-phase path (unchanged).
// Quarters 512..575 = R13's verified 128^2/BK=64 4-slot ring (0 conflicts).
// ---------------------------------------------------------------------------
__global__ __launch_bounds__(512, 2) void gemm_fused(const bf16_t* __restrict__ E,
                                                     const int* __restrict__ labels,
                                                     float* __restrict__ sumExp,
                                                     float* __restrict__ posSum,
                                                     float* __restrict__ out,
                                                     int* __restrict__ cnt) {
    __shared__ bf16_t As[2][2][128 * 64];   // 64 KB (quarter: 4-slot ring carve)
    __shared__ bf16_t Bs[2][2][128 * 64];   // 64 KB  (total 131072 B)

    const int tid  = threadIdx.x;
    const int wave = tid >> 6;
    const int lane = tid & 63;
    const int lr   = lane & 15;
    const int q    = lane >> 4;
    const float invT = 1.0f / 0.07f;

    const int su0 = ((0 + q) ^ (lane & 7)) * 16;     // k = 0 (128B-row swizzle)
    const int su1 = ((4 + q) ^ (lane & 7)) * 16;     // k = 1

    if (blockIdx.x >= NFULL) {
        // ===================================================================
        // QUARTER PATH (tail): 128x128, BK=64, 4-slot LDS ring, single phase
        // per K-step, counted vmcnt(8) (2 K-tiles always in flight).
        // All quarters strictly below the diagonal.
        // ===================================================================
        const int qb = (int)blockIdx.x - NFULL;     // 0..63
        const int p  = qb >> 2, qd = qb & 3;
        const int rowStart = 31 * BM + (qd >> 1) * 128;
        const int colStart = p * BM + (qd & 1) * 128;
        const int wm2 = wave >> 2;      // 0..1 : 64-row half
        const int wn2 = wave & 3;       // 0..3 : 32-col strip
        char* Aflat = (char*)&As[0][0][0];
        char* Bflat = (char*)&Bs[0][0][0];

        f32x4 acc[4][2];
        #pragma unroll
        for (int m = 0; m < 4; ++m) { acc[m][0] = {0,0,0,0}; acc[m][1] = {0,0,0,0}; }

        const int r0  = tid >> 3;                    // 0..63
        const int lu0 = (tid & 7) ^ (r0 & 7);
        const char* gA = (const char*)(E + (size_t)rowStart * D) + (size_t)r0 * (D * 2) + lu0 * 16;
        const char* gB = (const char*)(E + (size_t)colStart * D) + (size_t)r0 * (D * 2) + lu0 * 16;

        #define QST(slot, kb) do {                                                       \
            const char* ga_ = gA + (kb);                                                 \
            const char* gb_ = gB + (kb);                                                 \
            char* la_ = Aflat + (slot) * 16384 + wave * 1024;                            \
            char* lb_ = Bflat + (slot) * 16384 + wave * 1024;                            \
            __builtin_amdgcn_global_load_lds((const __attribute__((address_space(1))) void*)ga_, \
                (__attribute__((address_space(3))) void*)la_, 16, 0, 0);                 \
            __builtin_amdgcn_global_load_lds(                                            \
                (const __attribute__((address_space(1))) void*)(ga_ + 64 * 2048),        \
                (__attribute__((address_space(3))) void*)(la_ + 8192), 16, 0, 0);        \
            __builtin_amdgcn_global_load_lds((const __attribute__((address_space(1))) void*)gb_, \
                (__attribute__((address_space(3))) void*)lb_, 16, 0, 0);                 \
            __builtin_amdgcn_global_load_lds(                                            \
                (const __attribute__((address_space(1))) void*)(gb_ + 64 * 2048),        \
                (__attribute__((address_space(3))) void*)(lb_ + 8192), 16, 0, 0);        \
        } while (0)

        QST(0, 0);
        QST(1, 128);
        QST(2, 256);
        asm volatile("s_waitcnt vmcnt(8)" ::: "memory");
        __builtin_amdgcn_sched_barrier(0);
        __builtin_amdgcn_s_barrier();

        #pragma unroll 1
        for (int s = 0; s < 16; ++s) {
            const int slot = s & 3;
            if (s <= 12) QST((s + 3) & 3, (s + 3) * 128);   // WAR ok: read in step s-1
            const char* aB = Aflat + slot * 16384 + (wm2 * 64 + lr) * 128;
            const char* bB = Bflat + slot * 16384 + (wn2 * 32 + lr) * 128;
            bf16x8 qa0[4], qa1[4], qb0v[2], qb1v[2];
            #pragma unroll
            for (int m_ = 0; m_ < 4; ++m_) {
                qa0[m_] = *(const bf16x8*)(aB + m_ * 2048 + su0);
                qa1[m_] = *(const bf16x8*)(aB + m_ * 2048 + su1);
            }
            qb0v[0] = *(const bf16x8*)(bB + su0);
            qb0v[1] = *(const bf16x8*)(bB + 2048 + su0);
            qb1v[0] = *(const bf16x8*)(bB + su1);
            qb1v[1] = *(const bf16x8*)(bB + 2048 + su1);
            asm volatile("s_waitcnt lgkmcnt(0)");
            __builtin_amdgcn_sched_barrier(0);
            __builtin_amdgcn_s_setprio(1);
            #pragma unroll
            for (int m_ = 0; m_ < 4; ++m_) {
                #pragma unroll
                for (int n_ = 0; n_ < 2; ++n_)
                    acc[m_][n_] = __builtin_amdgcn_mfma_f32_16x16x32_bf16(
                        qa0[m_], qb0v[n_], acc[m_][n_], 0, 0, 0);
            }
            #pragma unroll
            for (int m_ = 0; m_ < 4; ++m_) {
                #pragma unroll
                for (int n_ = 0; n_ < 2; ++n_)
                    acc[m_][n_] = __builtin_amdgcn_mfma_f32_16x16x32_bf16(
                        qa1[m_], qb1v[n_], acc[m_][n_], 0, 0, 0);
            }
            __builtin_amdgcn_s_setprio(0);
            if (s <= 12)      asm volatile("s_waitcnt vmcnt(8)" ::: "memory");
            else if (s == 13) asm volatile("s_waitcnt vmcnt(4)" ::: "memory");
            else              asm volatile("s_waitcnt vmcnt(0)" ::: "memory");
            __builtin_amdgcn_sched_barrier(0);
            __builtin_amdgcn_s_barrier();
        }

        // epilogue (always off-diagonal, gi != gj guaranteed)
        int lc[2];
        lc[0] = labels[colStart + wn2 * 32 + lr];
        lc[1] = labels[colStart + wn2 * 32 + 16 + lr];
        float colAll[2] = {0.f, 0.f}, colPos[2] = {0.f, 0.f};
        #pragma unroll
        for (int m = 0; m < 4; ++m) {
            #pragma unroll
            for (int e = 0; e < 4; ++e) {
                const int gi = rowStart + wm2 * 64 + m * 16 + q * 4 + e;
                const int li = labels[gi];
                float s_all = 0.f, s_pos = 0.f;
                #pragma unroll
                for (int n = 0; n < 2; ++n) {
                    const float v = __expf(acc[m][n][e] * invT);
                    const bool same = (lc[n] == li);
                    s_all += v;
                    if (same) s_pos += v;
                    colAll[n] += v;
                    if (same) colPos[n] += v;
                }
                #pragma unroll
                for (int off = 1; off < 16; off <<= 1) {
                    s_all += __shfl_xor(s_all, off, 64);
                    s_pos += __shfl_xor(s_pos, off, 64);
                }
                if (lr == 0) {
                    atomicAdd(&sumExp[gi], s_all);
                    atomicAdd(&posSum[gi], s_pos);
                }
            }
        }
        #pragma unroll
        for (int n = 0; n < 2; ++n) {
            float a = colAll[n], pp = colPos[n];
            a += __shfl_xor(a, 16, 64);  a += __shfl_xor(a, 32, 64);
            pp += __shfl_xor(pp, 16, 64); pp += __shfl_xor(pp, 32, 64);
            if (q == 0) {
                const int gj = colStart + wn2 * 32 + n * 16 + lr;
                atomicAdd(&sumExp[gj], a);
                atomicAdd(&posSum[gj], pp);
            }
        }
    } else {
    // =======================================================================
    // FULL PATH: R2's verified 256^2 / BK=64 / 8-phase kernel, unchanged.
    // =======================================================================
    const int f0 = (int)blockIdx.x;
    const int f  = (f0 & 7) * (NFULL / 8) + (f0 >> 3);     // XCD swizzle, 512%8==0
    const int b  = (f < 496) ? f : f + 16;                 // skip quartered tiles

    int ti = (int)((sqrtf(8.0f * (float)b + 1.0f) - 1.0f) * 0.5f);
    while ((ti + 1) * (ti + 2) / 2 <= b) ++ti;
    while (ti * (ti + 1) / 2 > b) --ti;
    const int tj = b - ti * (ti + 1) / 2;
    const bool isDiag = (ti == tj);

    const int wm   = wave >> 2;     // 0..1 : row half
    const int wn   = wave & 3;      // 0..3 : 64-col strip
    const int rowStart = ti * BM;
    const int colStart = tj * BM;

    f32x4 acc[8][4];
    #pragma unroll
    for (int m = 0; m < 8; ++m)
        #pragma unroll
        for (int n = 0; n < 4; ++n) acc[m][n] = {0.f, 0.f, 0.f, 0.f};

    const int r0  = tid >> 3;                    // 0..63 (second load adds 64 rows)
    const int lu0 = (tid & 7) ^ (r0 & 7);
    const char* gA = (const char*)(E + (size_t)rowStart * D) + (size_t)r0 * (D * 2) + lu0 * 16;
    const char* gB = (const char*)(E + (size_t)colStart * D) + (size_t)r0 * (D * 2) + lu0 * 16;

    #define STAGE_A(buf, h, kb) do {                                                     \
        const char* g0_ = gA + (size_t)(h) * (128 * 2048) + (kb);                        \
        char* l0_ = (char*)&As[buf][h][0] + wave * 1024;                                 \
        __builtin_amdgcn_global_load_lds((const __attribute__((address_space(1))) void*)g0_, \
            (__attribute__((address_space(3))) void*)l0_, 16, 0, 0);                     \
        __builtin_amdgcn_global_load_lds(                                                \
            (const __attribute__((address_space(1))) void*)(g0_ + 64 * 2048),            \
            (__attribute__((address_space(3))) void*)(l0_ + 8192), 16, 0, 0);            \
    } while (0)
    #define STAGE_B(buf, h, kb) do {                                                     \
        const char* g0_ = gB + (size_t)(h) * (128 * 2048) + (kb);                        \
        char* l0_ = (char*)&Bs[buf][h][0] + wave * 1024;                                 \
        __builtin_amdgcn_global_load_lds((const __attribute__((address_space(1))) void*)g0_, \
            (__attribute__((address_space(3))) void*)l0_, 16, 0, 0);                     \
        __builtin_amdgcn_global_load_lds(                                                \
            (const __attribute__((address_space(1))) void*)(g0_ + 64 * 2048),            \
            (__attribute__((address_space(3))) void*)(l0_ + 8192), 16, 0, 0);            \
    } while (0)

    const char* rA0 = (const char*)&As[0][wm][0] + lr * 128;
    const char* rA1 = (const char*)&As[1][wm][0] + lr * 128;
    const char* rB0 = (const char*)&Bs[0][wn >> 1][0] + (wn & 1) * 8192 + lr * 128;
    const char* rB1 = (const char*)&Bs[1][wn >> 1][0] + (wn & 1) * 8192 + lr * 128;

    #define LD_A4(DST, RBASE, MOFFB, SU) do {                                            \
        _Pragma("unroll")                                                                \
        for (int m_ = 0; m_ < 4; ++m_)                                                   \
            DST[m_] = *(const bf16x8*)((RBASE) + (MOFFB) + m_ * 2048 + (SU));            \
    } while (0)
    #define LD_B4(DST, RBASE, SU) do {                                                   \
        _Pragma("unroll")                                                                \
        for (int n_ = 0; n_ < 4; ++n_)                                                   \
            DST[n_] = *(const bf16x8*)((RBASE) + n_ * 2048 + (SU));                      \
    } while (0)
    #define MFMA_QUAD(AF, BF, MO) do {                                                   \
        _Pragma("unroll")                                                                \
        for (int m_ = 0; m_ < 4; ++m_) {                                                 \
            _Pragma("unroll")                                                            \
            for (int n_ = 0; n_ < 4; ++n_)                                               \
                acc[(MO) + m_][n_] = __builtin_amdgcn_mfma_f32_16x16x32_bf16(            \
                    AF[m_], BF[n_], acc[(MO) + m_][n_], 0, 0, 0);                        \
        }                                                                                \
    } while (0)

    bf16x8 a0[4], a1[4], bq0[4], bq1[4];

    STAGE_B(0, 0, 0);  STAGE_B(0, 1, 0);
    STAGE_A(0, 0, 0);  STAGE_A(0, 1, 0);
    STAGE_B(1, 0, 128); STAGE_B(1, 1, 128);
    asm volatile("s_waitcnt vmcnt(4)" ::: "memory");
    __builtin_amdgcn_sched_barrier(0);
    __builtin_amdgcn_s_barrier();

    #pragma unroll 1
    for (int it = 0; it < ITERS; ++it) {
        const bool lastIt = (it == ITERS - 1);
        const int kb1 = (2 * it + 1) * 128;
        const int kb2 = (2 * it + 2) * 128;
        const int kb3 = (2 * it + 3) * 128;

        LD_A4(a0, rA0, 0, su0);
        LD_B4(bq0, rB0, su0);
        STAGE_A(1, 0, kb1);
        PHASE_MID();
        MFMA_QUAD(a0, bq0, 0);
        PHASE_END();

        LD_A4(a1, rA0, 0, su1);
        LD_B4(bq1, rB0, su1);
        STAGE_A(1, 1, kb1);
        PHASE_MID();
        MFMA_QUAD(a1, bq1, 0);
        PHASE_END();

        LD_A4(a0, rA0, 8192, su0);
        if (!lastIt) STAGE_B(0, 0, kb2);
        PHASE_MID();
        MFMA_QUAD(a0, bq0, 4);
        PHASE_END();

        LD_A4(a1, rA0, 8192, su1);
        if (!lastIt) {
            STAGE_B(0, 1, kb2);
            asm volatile("s_waitcnt vmcnt(4)" ::: "memory");
        } else {
            asm volatile("s_waitcnt vmcnt(0)" ::: "memory");
        }
        __builtin_amdgcn_sched_barrier(0);
        PHASE_MID();
        MFMA_QUAD(a1, bq1, 4);
        PHASE_END();

        LD_A4(a0, rA1, 0, su0);
        LD_B4(bq0, rB1, su0);
        if (!lastIt) STAGE_A(0, 0, kb2);
        PHASE_MID();
        MFMA_QUAD(a0, bq0, 0);
        PHASE_END();

        LD_A4(a1, rA1, 0, su1);
        LD_B4(bq1, rB1, su1);
        if (!lastIt) STAGE_A(0, 1, kb2);
        PHASE_MID();
        MFMA_QUAD(a1, bq1, 0);
        PHASE_END();

        LD_A4(a0, rA1, 8192, su0);
        if (!lastIt) STAGE_B(1, 0, kb3);
        PHASE_MID();
        MFMA_QUAD(a0, bq0, 4);
        PHASE_END();

        LD_A4(a1, rA1, 8192, su1);
        if (!lastIt) {
            STAGE_B(1, 1, kb3);
            asm volatile("s_waitcnt vmcnt(4)" ::: "memory");
            __builtin_amdgcn_sched_barrier(0);
        }
        PHASE_MID();
        MFMA_QUAD(a1, bq1, 4);
        PHASE_END();
    }

    int lc[4];
    #pragma unroll
    for (int n = 0; n < 4; ++n)
        lc[n] = labels[colStart + wn * 64 + n * 16 + lr];

    float colAll[4] = {0.f, 0.f, 0.f, 0.f};
    float colPos[4] = {0.f, 0.f, 0.f, 0.f};
    #pragma unroll
    for (int m = 0; m < 8; ++m) {
        #pragma unroll
        for (int e = 0; e < 4; ++e) {
            const int rloc = wm * 128 + m * 16 + q * 4 + e;
            const int gi   = rowStart + rloc;
            const int li   = labels[gi];
            float s_all = 0.f, s_pos = 0.f;
            #pragma unroll
            for (int n = 0; n < 4; ++n) {
                const int cloc = wn * 64 + n * 16 + lr;
                const int gj   = colStart + cloc;
                const float v  = __expf(acc[m][n][e] * invT);
                const bool same = (lc[n] == li);
                s_all += v;
                if (same && gi != gj) s_pos += v;
                if (!isDiag) {
                    colAll[n] += v;
                    if (same) colPos[n] += v;
                }
            }
            #pragma unroll
            for (int off = 1; off < 16; off <<= 1) {
                s_all += __shfl_xor(s_all, off, 64);
                s_pos += __shfl_xor(s_pos, off, 64);
            }
            if (lr == 0) {
                atomicAdd(&sumExp[gi], s_all);
                atomicAdd(&posSum[gi], s_pos);
            }
        }
    }
    if (!isDiag) {
        #pragma unroll
        for (int n = 0; n < 4; ++n) {
            float a = colAll[n], p = colPos[n];
            a += __shfl_xor(a, 16, 64);  a += __shfl_xor(a, 32, 64);
            p += __shfl_xor(p, 16, 64);  p += __shfl_xor(p, 32, 64);
            if (q == 0) {
                const int gj = colStart + wn * 64 + n * 16 + lr;
                atomicAdd(&sumExp[gj], a);
                atomicAdd(&posSum[gj], p);
            }
        }
    }
    }  // end full path

    // =======================================================================
    // Merged finalize — fence-free. __syncthreads() drains each wave's
    // outstanding (device-scope, coherence-point) atomics; tid0 then bumps
    // the done-counter. The 576th block sees all atomics performed and
    // reduces loss = mean(log(sumExp/posSum)) via agent-scope loads.
    // =======================================================================
    __syncthreads();
    int* lastFlag = (int*)&As[0][0][0];          // LDS reuse (all LDS use done)
    float* redf   = (float*)((char*)&As[0][0][0] + 64);
    if (tid == 0) *lastFlag = (atomicAdd(cnt, 1) == NBLK - 1) ? 1 : 0;
    __syncthreads();
    if (*lastFlag) {
        float s = 0.f;
        for (int i = tid; i < N; i += 512) {
            const float se = __hip_atomic_load(&sumExp[i], __ATOMIC_RELAXED,
                                               __HIP_MEMORY_SCOPE_AGENT);
            const float ps = __hip_atomic_load(&posSum[i], __ATOMIC_RELAXED,
                                               __HIP_MEMORY_SCOPE_AGENT);
            s += __logf(se / ps);
        }
        #pragma unroll
        for (int off = 32; off >= 1; off >>= 1) s += __shfl_xor(s, off, 64);
        if (lane == 0) redf[wave] = s;
        __syncthreads();
        if (tid == 0) {
            float t = 0.f;
            #pragma unroll
            for (int i = 0; i < 8; ++i) t += redf[i];
            out[0] = t / (float)N;
        }
    }
}

extern "C" void kernel_launch(void* const* d_in, const int* in_sizes, int n_in,
                              void* d_out, int out_size, void* d_ws, size_t ws_size,
                              hipStream_t stream) {
    const float* emb    = (const float*)d_in[0];
    const int*   labels = (const int*)d_in[1];
    float* out = (float*)d_out;

    // ws layout: [sumExp: N floats][posSum: N floats][cnt + pad: 16B][EN: N*D bf16]
    float*  sumExp = (float*)d_ws;
    float*  posSum = sumExp + N;
    int*    cnt    = (int*)((char*)d_ws + (size_t)2 * N * sizeof(float));
    bf16_t* EN     = (bf16_t*)((char*)d_ws + (size_t)2 * N * sizeof(float) + 16);

    norm_cast<<<N / 4, 256, 0, stream>>>(emb, EN, sumExp, posSum, cnt);

    gemm_fused<<<NBLK, 512, 0, stream>>>(EN, labels, sumExp, posSum, out, cnt);
}

// Round 15
// 212.012 us; speedup vs baseline: 1.0592x; 1.0332x over previous
//
#include <hip/hip_runtime.h>
#include <hip/hip_bf16.h>
#include <math.h>

#define N 8192
#define D 1024
#define BM 256
#define BK 64
#define NQUART 64                       // 16 tiles (ti=31, tj=0..15) x 4 quadrants
#define NFULL 512                       // 528 - 16 quartered tiles
#define NBLK (NFULL + NQUART)           // 576: fulls 0..511, quarters 512..575
#define ITERS 8                         // full path: 16 K-tiles / 2 per iter

typedef __bf16 bf16_t;
typedef bf16_t bf16x4 __attribute__((ext_vector_type(4)));
typedef bf16_t bf16x8 __attribute__((ext_vector_type(8)));
typedef float f32x4 __attribute__((ext_vector_type(4)));

// ---------------------------------------------------------------------------
// Kernel 1: L2-normalize each row, cast to bf16. Wave-per-row. Also zeroes
// sumExp/posSum (replaces the memset dispatch).
// ---------------------------------------------------------------------------
__global__ __launch_bounds__(256) void norm_cast(const float* __restrict__ in,
                                                 bf16_t* __restrict__ out,
                                                 float* __restrict__ sumExp,
                                                 float* __restrict__ posSum) {
    const int wave = threadIdx.x >> 6, lane = threadIdx.x & 63;
    const int row  = blockIdx.x * 4 + wave;
    const float4* src = (const float4*)(in + (size_t)row * D);
    float4 v[4];
    float ss = 0.f;
    #pragma unroll
    for (int i = 0; i < 4; ++i) {
        v[i] = src[lane + 64 * i];
        ss += v[i].x * v[i].x + v[i].y * v[i].y + v[i].z * v[i].z + v[i].w * v[i].w;
    }
    #pragma unroll
    for (int off = 32; off >= 1; off >>= 1) ss += __shfl_xor(ss, off, 64);
    const float scale = 1.0f / fmaxf(sqrtf(ss), 1e-12f);
    bf16x4* dst = (bf16x4*)(out + (size_t)row * D);
    #pragma unroll
    for (int i = 0; i < 4; ++i) {
        bf16x4 o;
        o[0] = (bf16_t)(v[i].x * scale);
        o[1] = (bf16_t)(v[i].y * scale);
        o[2] = (bf16_t)(v[i].z * scale);
        o[3] = (bf16_t)(v[i].w * scale);
        dst[lane + 64 * i] = o;
    }
    if (lane == 0) { sumExp[row] = 0.f; posSum[row] = 0.f; }
}

#define PHASE_MID() do {                                                             \
    __builtin_amdgcn_s_barrier();                                                    \
    asm volatile("s_waitcnt lgkmcnt(0)");                                            \
    __builtin_amdgcn_sched_barrier(0);                                               \
    __builtin_amdgcn_s_setprio(1);                                                   \
} while (0)
#define PHASE_END() do {                                                             \
    __builtin_amdgcn_s_setprio(0);                                                   \
    __builtin_amdgcn_s_barrier();                                                    \
} while (0)

// ---------------------------------------------------------------------------
// Kernel 2: fused symmetric  C = E·E^T / T -> exp -> masked row+col sums.
// R15 = R12's 3-kernel structure (best gemm codegen: quarter-path return, no
// reduction tail) with R13's verified conflict-free BK=64 4-slot-ring quarter
// replacing R12's bank-degenerate BK=128 quarter.
// Fulls 0..511 = R2's verified 256^2/BK=64/8-phase path (unchanged).
// Quarters 512..575 fill the dispatch tail (LPT).
// ---------------------------------------------------------------------------
__global__ __launch_bounds__(512, 2) void gemm_fused(const bf16_t* __restrict__ E,
                                                     const int* __restrict__ labels,
                                                     float* __restrict__ sumExp,
                                                     float* __restrict__ posSum) {
    __shared__ bf16_t As[2][2][128 * 64];   // 64 KB (quarter: 4-slot ring carve)
    __shared__ bf16_t Bs[2][2][128 * 64];   // 64 KB  (total 131072 B)

    const int tid  = threadIdx.x;
    const int wave = tid >> 6;
    const int lane = tid & 63;
    const int lr   = lane & 15;
    const int q    = lane >> 4;
    const float invT = 1.0f / 0.07f;

    const int su0 = ((0 + q) ^ (lane & 7)) * 16;     // k = 0 (128B-row swizzle)
    const int su1 = ((4 + q) ^ (lane & 7)) * 16;     // k = 1

    if (blockIdx.x >= NFULL) {
        // ===================================================================
        // QUARTER PATH (tail): 128x128, BK=64, 4-slot LDS ring, single phase
        // per K-step, counted vmcnt(8) (2 K-tiles always in flight).
        // All quarters strictly below the diagonal. [R13-verified, 0 confl]
        // ===================================================================
        const int qb = (int)blockIdx.x - NFULL;     // 0..63
        const int p  = qb >> 2, qd = qb & 3;
        const int rowStart = 31 * BM + (qd >> 1) * 128;
        const int colStart = p * BM + (qd & 1) * 128;
        const int wm2 = wave >> 2;      // 0..1 : 64-row half
        const int wn2 = wave & 3;       // 0..3 : 32-col strip
        char* Aflat = (char*)&As[0][0][0];
        char* Bflat = (char*)&Bs[0][0][0];

        f32x4 acc[4][2];
        #pragma unroll
        for (int m = 0; m < 4; ++m) { acc[m][0] = {0,0,0,0}; acc[m][1] = {0,0,0,0}; }

        const int r0  = tid >> 3;                    // 0..63
        const int lu0 = (tid & 7) ^ (r0 & 7);
        const char* gA = (const char*)(E + (size_t)rowStart * D) + (size_t)r0 * (D * 2) + lu0 * 16;
        const char* gB = (const char*)(E + (size_t)colStart * D) + (size_t)r0 * (D * 2) + lu0 * 16;

        #define QST(slot, kb) do {                                                       \
            const char* ga_ = gA + (kb);                                                 \
            const char* gb_ = gB + (kb);                                                 \
            char* la_ = Aflat + (slot) * 16384 + wave * 1024;                            \
            char* lb_ = Bflat + (slot) * 16384 + wave * 1024;                            \
            __builtin_amdgcn_global_load_lds((const __attribute__((address_space(1))) void*)ga_, \
                (__attribute__((address_space(3))) void*)la_, 16, 0, 0);                 \
            __builtin_amdgcn_global_load_lds(                                            \
                (const __attribute__((address_space(1))) void*)(ga_ + 64 * 2048),        \
                (__attribute__((address_space(3))) void*)(la_ + 8192), 16, 0, 0);        \
            __builtin_amdgcn_global_load_lds((const __attribute__((address_space(1))) void*)gb_, \
                (__attribute__((address_space(3))) void*)lb_, 16, 0, 0);                 \
            __builtin_amdgcn_global_load_lds(                                            \
                (const __attribute__((address_space(1))) void*)(gb_ + 64 * 2048),        \
                (__attribute__((address_space(3))) void*)(lb_ + 8192), 16, 0, 0);        \
        } while (0)

        QST(0, 0);
        QST(1, 128);
        QST(2, 256);
        asm volatile("s_waitcnt vmcnt(8)" ::: "memory");
        __builtin_amdgcn_sched_barrier(0);
        __builtin_amdgcn_s_barrier();

        #pragma unroll 1
        for (int s = 0; s < 16; ++s) {
            const int slot = s & 3;
            if (s <= 12) QST((s + 3) & 3, (s + 3) * 128);   // WAR ok: read in step s-1
            const char* aB = Aflat + slot * 16384 + (wm2 * 64 + lr) * 128;
            const char* bB = Bflat + slot * 16384 + (wn2 * 32 + lr) * 128;
            bf16x8 qa0[4], qa1[4], qb0v[2], qb1v[2];
            #pragma unroll
            for (int m_ = 0; m_ < 4; ++m_) {
                qa0[m_] = *(const bf16x8*)(aB + m_ * 2048 + su0);
                qa1[m_] = *(const bf16x8*)(aB + m_ * 2048 + su1);
            }
            qb0v[0] = *(const bf16x8*)(bB + su0);
            qb0v[1] = *(const bf16x8*)(bB + 2048 + su0);
            qb1v[0] = *(const bf16x8*)(bB + su1);
            qb1v[1] = *(const bf16x8*)(bB + 2048 + su1);
            asm volatile("s_waitcnt lgkmcnt(0)");
            __builtin_amdgcn_sched_barrier(0);
            __builtin_amdgcn_s_setprio(1);
            #pragma unroll
            for (int m_ = 0; m_ < 4; ++m_) {
                #pragma unroll
                for (int n_ = 0; n_ < 2; ++n_)
                    acc[m_][n_] = __builtin_amdgcn_mfma_f32_16x16x32_bf16(
                        qa0[m_], qb0v[n_], acc[m_][n_], 0, 0, 0);
            }
            #pragma unroll
            for (int m_ = 0; m_ < 4; ++m_) {
                #pragma unroll
                for (int n_ = 0; n_ < 2; ++n_)
                    acc[m_][n_] = __builtin_amdgcn_mfma_f32_16x16x32_bf16(
                        qa1[m_], qb1v[n_], acc[m_][n_], 0, 0, 0);
            }
            __builtin_amdgcn_s_setprio(0);
            if (s <= 12)      asm volatile("s_waitcnt vmcnt(8)" ::: "memory");
            else if (s == 13) asm volatile("s_waitcnt vmcnt(4)" ::: "memory");
            else              asm volatile("s_waitcnt vmcnt(0)" ::: "memory");
            __builtin_amdgcn_sched_barrier(0);
            __builtin_amdgcn_s_barrier();
        }

        // epilogue (always off-diagonal, gi != gj guaranteed)
        int lc[2];
        lc[0] = labels[colStart + wn2 * 32 + lr];
        lc[1] = labels[colStart + wn2 * 32 + 16 + lr];
        float colAll[2] = {0.f, 0.f}, colPos[2] = {0.f, 0.f};
        #pragma unroll
        for (int m = 0; m < 4; ++m) {
            #pragma unroll
            for (int e = 0; e < 4; ++e) {
                const int gi = rowStart + wm2 * 64 + m * 16 + q * 4 + e;
                const int li = labels[gi];
                float s_all = 0.f, s_pos = 0.f;
                #pragma unroll
                for (int n = 0; n < 2; ++n) {
                    const float v = __expf(acc[m][n][e] * invT);
                    const bool same = (lc[n] == li);
                    s_all += v;
                    if (same) s_pos += v;
                    colAll[n] += v;
                    if (same) colPos[n] += v;
                }
                #pragma unroll
                for (int off = 1; off < 16; off <<= 1) {
                    s_all += __shfl_xor(s_all, off, 64);
                    s_pos += __shfl_xor(s_pos, off, 64);
                }
                if (lr == 0) {
                    atomicAdd(&sumExp[gi], s_all);
                    atomicAdd(&posSum[gi], s_pos);
                }
            }
        }
        #pragma unroll
        for (int n = 0; n < 2; ++n) {
            float a = colAll[n], pp = colPos[n];
            a += __shfl_xor(a, 16, 64);  a += __shfl_xor(a, 32, 64);
            pp += __shfl_xor(pp, 16, 64); pp += __shfl_xor(pp, 32, 64);
            if (q == 0) {
                const int gj = colStart + wn2 * 32 + n * 16 + lr;
                atomicAdd(&sumExp[gj], a);
                atomicAdd(&posSum[gj], pp);
            }
        }
        return;
    }

    // =======================================================================
    // FULL PATH: R2's verified 256^2 / BK=64 / 8-phase kernel, unchanged.
    // =======================================================================
    const int f0 = (int)blockIdx.x;
    const int f  = (f0 & 7) * (NFULL / 8) + (f0 >> 3);     // XCD swizzle, 512%8==0
    const int b  = (f < 496) ? f : f + 16;                 // skip quartered tiles

    int ti = (int)((sqrtf(8.0f * (float)b + 1.0f) - 1.0f) * 0.5f);
    while ((ti + 1) * (ti + 2) / 2 <= b) ++ti;
    while (ti * (ti + 1) / 2 > b) --ti;
    const int tj = b - ti * (ti + 1) / 2;
    const bool isDiag = (ti == tj);

    const int wm   = wave >> 2;     // 0..1 : row half
    const int wn   = wave & 3;      // 0..3 : 64-col strip
    const int rowStart = ti * BM;
    const int colStart = tj * BM;

    f32x4 acc[8][4];
    #pragma unroll
    for (int m = 0; m < 8; ++m)
        #pragma unroll
        for (int n = 0; n < 4; ++n) acc[m][n] = {0.f, 0.f, 0.f, 0.f};

    const int r0  = tid >> 3;                    // 0..63 (second load adds 64 rows)
    const int lu0 = (tid & 7) ^ (r0 & 7);
    const char* gA = (const char*)(E + (size_t)rowStart * D) + (size_t)r0 * (D * 2) + lu0 * 16;
    const char* gB = (const char*)(E + (size_t)colStart * D) + (size_t)r0 * (D * 2) + lu0 * 16;

    #define STAGE_A(buf, h, kb) do {                                                     \
        const char* g0_ = gA + (size_t)(h) * (128 * 2048) + (kb);                        \
        char* l0_ = (char*)&As[buf][h][0] + wave * 1024;                                 \
        __builtin_amdgcn_global_load_lds((const __attribute__((address_space(1))) void*)g0_, \
            (__attribute__((address_space(3))) void*)l0_, 16, 0, 0);                     \
        __builtin_amdgcn_global_load_lds(                                                \
            (const __attribute__((address_space(1))) void*)(g0_ + 64 * 2048),            \
            (__attribute__((address_space(3))) void*)(l0_ + 8192), 16, 0, 0);            \
    } while (0)
    #define STAGE_B(buf, h, kb) do {                                                     \
        const char* g0_ = gB + (size_t)(h) * (128 * 2048) + (kb);                        \
        char* l0_ = (char*)&Bs[buf][h][0] + wave * 1024;                                 \
        __builtin_amdgcn_global_load_lds((const __attribute__((address_space(1))) void*)g0_, \
            (__attribute__((address_space(3))) void*)l0_, 16, 0, 0);                     \
        __builtin_amdgcn_global_load_lds(                                                \
            (const __attribute__((address_space(1))) void*)(g0_ + 64 * 2048),            \
            (__attribute__((address_space(3))) void*)(l0_ + 8192), 16, 0, 0);            \
    } while (0)

    const char* rA0 = (const char*)&As[0][wm][0] + lr * 128;
    const char* rA1 = (const char*)&As[1][wm][0] + lr * 128;
    const char* rB0 = (const char*)&Bs[0][wn >> 1][0] + (wn & 1) * 8192 + lr * 128;
    const char* rB1 = (const char*)&Bs[1][wn >> 1][0] + (wn & 1) * 8192 + lr * 128;

    #define LD_A4(DST, RBASE, MOFFB, SU) do {                                            \
        _Pragma("unroll")                                                                \
        for (int m_ = 0; m_ < 4; ++m_)                                                   \
            DST[m_] = *(const bf16x8*)((RBASE) + (MOFFB) + m_ * 2048 + (SU));            \
    } while (0)
    #define LD_B4(DST, RBASE, SU) do {                                                   \
        _Pragma("unroll")                                                                \
        for (int n_ = 0; n_ < 4; ++n_)                                                   \
            DST[n_] = *(const bf16x8*)((RBASE) + n_ * 2048 + (SU));                      \
    } while (0)
    #define MFMA_QUAD(AF, BF, MO) do {                                                   \
        _Pragma("unroll")                                                                \
        for (int m_ = 0; m_ < 4; ++m_) {                                                 \
            _Pragma("unroll")                                                            \
            for (int n_ = 0; n_ < 4; ++n_)                                               \
                acc[(MO) + m_][n_] = __builtin_amdgcn_mfma_f32_16x16x32_bf16(            \
                    AF[m_], BF[n_], acc[(MO) + m_][n_], 0, 0, 0);                        \
        }                                                                                \
    } while (0)

    bf16x8 a0[4], a1[4], bq0[4], bq1[4];

    STAGE_B(0, 0, 0);  STAGE_B(0, 1, 0);
    STAGE_A(0, 0, 0);  STAGE_A(0, 1, 0);
    STAGE_B(1, 0, 128); STAGE_B(1, 1, 128);
    asm volatile("s_waitcnt vmcnt(4)" ::: "memory");
    __builtin_amdgcn_sched_barrier(0);
    __builtin_amdgcn_s_barrier();

    #pragma unroll 1
    for (int it = 0; it < ITERS; ++it) {
        const bool lastIt = (it == ITERS - 1);
        const int kb1 = (2 * it + 1) * 128;
        const int kb2 = (2 * it + 2) * 128;
        const int kb3 = (2 * it + 3) * 128;

        LD_A4(a0, rA0, 0, su0);
        LD_B4(bq0, rB0, su0);
        STAGE_A(1, 0, kb1);
        PHASE_MID();
        MFMA_QUAD(a0, bq0, 0);
        PHASE_END();

        LD_A4(a1, rA0, 0, su1);
        LD_B4(bq1, rB0, su1);
        STAGE_A(1, 1, kb1);
        PHASE_MID();
        MFMA_QUAD(a1, bq1, 0);
        PHASE_END();

        LD_A4(a0, rA0, 8192, su0);
        if (!lastIt) STAGE_B(0, 0, kb2);
        PHASE_MID();
        MFMA_QUAD(a0, bq0, 4);
        PHASE_END();

        LD_A4(a1, rA0, 8192, su1);
        if (!lastIt) {
            STAGE_B(0, 1, kb2);
            asm volatile("s_waitcnt vmcnt(4)" ::: "memory");
        } else {
            asm volatile("s_waitcnt vmcnt(0)" ::: "memory");
        }
        __builtin_amdgcn_sched_barrier(0);
        PHASE_MID();
        MFMA_QUAD(a1, bq1, 4);
        PHASE_END();

        LD_A4(a0, rA1, 0, su0);
        LD_B4(bq0, rB1, su0);
        if (!lastIt) STAGE_A(0, 0, kb2);
        PHASE_MID();
        MFMA_QUAD(a0, bq0, 0);
        PHASE_END();

        LD_A4(a1, rA1, 0, su1);
        LD_B4(bq1, rB1, su1);
        if (!lastIt) STAGE_A(0, 1, kb2);
        PHASE_MID();
        MFMA_QUAD(a1, bq1, 0);
        PHASE_END();

        LD_A4(a0, rA1, 8192, su0);
        if (!lastIt) STAGE_B(1, 0, kb3);
        PHASE_MID();
        MFMA_QUAD(a0, bq0, 4);
        PHASE_END();

        LD_A4(a1, rA1, 8192, su1);
        if (!lastIt) {
            STAGE_B(1, 1, kb3);
            asm volatile("s_waitcnt vmcnt(4)" ::: "memory");
            __builtin_amdgcn_sched_barrier(0);
        }
        PHASE_MID();
        MFMA_QUAD(a1, bq1, 4);
        PHASE_END();
    }

    int lc[4];
    #pragma unroll
    for (int n = 0; n < 4; ++n)
        lc[n] = labels[colStart + wn * 64 + n * 16 + lr];

    float colAll[4] = {0.f, 0.f, 0.f, 0.f};
    float colPos[4] = {0.f, 0.f, 0.f, 0.f};
    #pragma unroll
    for (int m = 0; m < 8; ++m) {
        #pragma unroll
        for (int e = 0; e < 4; ++e) {
            const int rloc = wm * 128 + m * 16 + q * 4 + e;
            const int gi   = rowStart + rloc;
            const int li   = labels[gi];
            float s_all = 0.f, s_pos = 0.f;
            #pragma unroll
            for (int n = 0; n < 4; ++n) {
                const int cloc = wn * 64 + n * 16 + lr;
                const int gj   = colStart + cloc;
                const float v  = __expf(acc[m][n][e] * invT);
                const bool same = (lc[n] == li);
                s_all += v;
                if (same && gi != gj) s_pos += v;
                if (!isDiag) {
                    colAll[n] += v;
                    if (same) colPos[n] += v;
                }
            }
            #pragma unroll
            for (int off = 1; off < 16; off <<= 1) {
                s_all += __shfl_xor(s_all, off, 64);
                s_pos += __shfl_xor(s_pos, off, 64);
            }
            if (lr == 0) {
                atomicAdd(&sumExp[gi], s_all);
                atomicAdd(&posSum[gi], s_pos);
            }
        }
    }
    if (!isDiag) {
        #pragma unroll
        for (int n = 0; n < 4; ++n) {
            float a = colAll[n], p = colPos[n];
            a += __shfl_xor(a, 16, 64);  a += __shfl_xor(a, 32, 64);
            p += __shfl_xor(p, 16, 64);  p += __shfl_xor(p, 32, 64);
            if (q == 0) {
                const int gj = colStart + wn * 64 + n * 16 + lr;
                atomicAdd(&sumExp[gj], a);
                atomicAdd(&posSum[gj], p);
            }
        }
    }
}

// ---------------------------------------------------------------------------
// Kernel 3: loss_i = log(sumExp_i / posSum_i); out = mean(loss).
// ---------------------------------------------------------------------------
__global__ __launch_bounds__(1024) void finalize(const float* __restrict__ sumExp,
                                                 const float* __restrict__ posSum,
                                                 float* __restrict__ out) {
    const int tid = threadIdx.x;
    float s = 0.f;
    #pragma unroll
    for (int i = tid; i < N; i += 1024)
        s += __logf(sumExp[i] / posSum[i]);
    #pragma unroll
    for (int off = 32; off >= 1; off >>= 1) s += __shfl_xor(s, off, 64);
    __shared__ float red[16];
    if ((tid & 63) == 0) red[tid >> 6] = s;
    __syncthreads();
    if (tid == 0) {
        float t = 0.f;
        #pragma unroll
        for (int i = 0; i < 16; ++i) t += red[i];
        out[0] = t / (float)N;
    }
}

extern "C" void kernel_launch(void* const* d_in, const int* in_sizes, int n_in,
                              void* d_out, int out_size, void* d_ws, size_t ws_size,
                              hipStream_t stream) {
    const float* emb    = (const float*)d_in[0];
    const int*   labels = (const int*)d_in[1];
    float* out = (float*)d_out;

    // ws layout: [sumExp: N floats][posSum: N floats][EN: N*D bf16]
    float*  sumExp = (float*)d_ws;
    float*  posSum = sumExp + N;
    bf16_t* EN     = (bf16_t*)((char*)d_ws + (size_t)2 * N * sizeof(float));

    norm_cast<<<N / 4, 256, 0, stream>>>(emb, EN, sumExp, posSum);

    gemm_fused<<<NBLK, 512, 0, stream>>>(EN, labels, sumExp, posSum);

    finalize<<<1, 1024, 0, stream>>>(sumExp, posSum, out);
}

// Round 16
// 204.397 us; speedup vs baseline: 1.0987x; 1.0373x over previous
//
#include <hip/hip_runtime.h>
#include <hip/hip_bf16.h>
#include <math.h>

#define N 8192
#define D 1024
#define BM 256
#define BK 64
#define NTAIL 128                       // 16 tiles (ti=31, tj=0..15) x 2 row-halves x 4 col-64s
#define NFULL 512                       // 528 - 16 split tiles
#define NBLK (NFULL + NTAIL)            // 640: fulls 0..511, tails 512..639
#define ITERS 8                         // full path: 16 K-tiles / 2 per iter

typedef __bf16 bf16_t;
typedef bf16_t bf16x4 __attribute__((ext_vector_type(4)));
typedef bf16_t bf16x8 __attribute__((ext_vector_type(8)));
typedef float f32x4 __attribute__((ext_vector_type(4)));

// ---------------------------------------------------------------------------
// Kernel 1: L2-normalize each row, cast to bf16. Wave-per-row. Also zeroes
// sumExp/posSum (replaces the memset dispatch).
// ---------------------------------------------------------------------------
__global__ __launch_bounds__(256) void norm_cast(const float* __restrict__ in,
                                                 bf16_t* __restrict__ out,
                                                 float* __restrict__ sumExp,
                                                 float* __restrict__ posSum) {
    const int wave = threadIdx.x >> 6, lane = threadIdx.x & 63;
    const int row  = blockIdx.x * 4 + wave;
    const float4* src = (const float4*)(in + (size_t)row * D);
    float4 v[4];
    float ss = 0.f;
    #pragma unroll
    for (int i = 0; i < 4; ++i) {
        v[i] = src[lane + 64 * i];
        ss += v[i].x * v[i].x + v[i].y * v[i].y + v[i].z * v[i].z + v[i].w * v[i].w;
    }
    #pragma unroll
    for (int off = 32; off >= 1; off >>= 1) ss += __shfl_xor(ss, off, 64);
    const float scale = 1.0f / fmaxf(sqrtf(ss), 1e-12f);
    bf16x4* dst = (bf16x4*)(out + (size_t)row * D);
    #pragma unroll
    for (int i = 0; i < 4; ++i) {
        bf16x4 o;
        o[0] = (bf16_t)(v[i].x * scale);
        o[1] = (bf16_t)(v[i].y * scale);
        o[2] = (bf16_t)(v[i].z * scale);
        o[3] = (bf16_t)(v[i].w * scale);
        dst[lane + 64 * i] = o;
    }
    if (lane == 0) { sumExp[row] = 0.f; posSum[row] = 0.f; }
}

#define PHASE_MID() do {                                                             \
    __builtin_amdgcn_s_barrier();                                                    \
    asm volatile("s_waitcnt lgkmcnt(0)");                                            \
    __builtin_amdgcn_sched_barrier(0);                                               \
    __builtin_amdgcn_s_setprio(1);                                                   \
} while (0)
#define PHASE_END() do {                                                             \
    __builtin_amdgcn_s_setprio(0);                                                   \
    __builtin_amdgcn_s_barrier();                                                    \
} while (0)

// ---------------------------------------------------------------------------
// Kernel 2: fused symmetric  C = E·E^T / T -> exp -> masked row+col sums.
// R16 = R15 with the tail split 2x finer: 128 blocks of 128x64 (vs 64 of
// 128^2) so the dispatch tail runs on 128 CUs instead of 64. Tail uses a
// 4-slot ring (A 4x16KB + B 4x8KB = 96 KB), 3 gloads/K-tile, counted
// vmcnt(6) (2 K-tiles in flight), proven 128B-row swizzle.
// Fulls 0..511 = R2's verified 256^2/BK=64/8-phase path (unchanged).
// ---------------------------------------------------------------------------
__global__ __launch_bounds__(512, 2) void gemm_fused(const bf16_t* __restrict__ E,
                                                     const int* __restrict__ labels,
                                                     float* __restrict__ sumExp,
                                                     float* __restrict__ posSum) {
    __shared__ bf16_t As[2][2][128 * 64];   // 64 KB (tail: A 4-slot ring carve)
    __shared__ bf16_t Bs[2][2][128 * 64];   // 64 KB (tail: B 4-slot ring carve)

    const int tid  = threadIdx.x;
    const int wave = tid >> 6;
    const int lane = tid & 63;
    const int lr   = lane & 15;
    const int q    = lane >> 4;
    const float invT = 1.0f / 0.07f;

    const int su0 = ((0 + q) ^ (lane & 7)) * 16;     // k = 0 (128B-row swizzle)
    const int su1 = ((4 + q) ^ (lane & 7)) * 16;     // k = 1

    if (blockIdx.x >= NFULL) {
        // ===================================================================
        // TAIL PATH: 128x64 blocks (2 per former quarter), BK=64, 4-slot
        // ring, single phase per K-step, counted vmcnt(6).
        // All tails strictly below the diagonal (rows>=7936, cols<=4095).
        // ===================================================================
        const int tb = (int)blockIdx.x - NFULL;     // 0..127
        const int p  = tb >> 3;                      // tile col 0..15
        const int h  = (tb >> 2) & 1;                // row half
        const int c  = tb & 3;                       // 64-col quarter
        const int rowStart = 31 * BM + h * 128;
        const int colStart = p * BM + c * 64;
        const int wm3 = wave >> 1;      // 0..3 : 32-row group
        const int wn3 = wave & 1;       // 0..1 : 32-col group
        char* Aflat = (char*)&As[0][0][0];   // 4 x 16 KB (128 rows x 128B)
        char* Bflat = (char*)&Bs[0][0][0];   // 4 x  8 KB ( 64 rows x 128B)

        f32x4 acc[2][2];
        #pragma unroll
        for (int m = 0; m < 2; ++m) { acc[m][0] = {0,0,0,0}; acc[m][1] = {0,0,0,0}; }

        const int r0  = tid >> 3;                    // 0..63
        const int lu0 = (tid & 7) ^ (r0 & 7);
        const char* gA = (const char*)(E + (size_t)rowStart * D) + (size_t)r0 * (D * 2) + lu0 * 16;
        const char* gB = (const char*)(E + (size_t)colStart * D) + (size_t)r0 * (D * 2) + lu0 * 16;

        // stage K-tile into ring slot: A rows 0-63, 64-127; B rows 0-63.
        #define TST(slot, kb) do {                                                       \
            const char* ga_ = gA + (kb);                                                 \
            const char* gb_ = gB + (kb);                                                 \
            char* la_ = Aflat + (slot) * 16384 + wave * 1024;                            \
            char* lb_ = Bflat + (slot) * 8192 + wave * 1024;                             \
            __builtin_amdgcn_global_load_lds((const __attribute__((address_space(1))) void*)ga_, \
                (__attribute__((address_space(3))) void*)la_, 16, 0, 0);                 \
            __builtin_amdgcn_global_load_lds(                                            \
                (const __attribute__((address_space(1))) void*)(ga_ + 64 * 2048),        \
                (__attribute__((address_space(3))) void*)(la_ + 8192), 16, 0, 0);        \
            __builtin_amdgcn_global_load_lds((const __attribute__((address_space(1))) void*)gb_, \
                (__attribute__((address_space(3))) void*)lb_, 16, 0, 0);                 \
        } while (0)

        // prologue: stage T0,T1,T2 (9 loads); vmcnt(6) -> T0's 3 landed.
        TST(0, 0);
        TST(1, 128);
        TST(2, 256);
        asm volatile("s_waitcnt vmcnt(6)" ::: "memory");
        __builtin_amdgcn_sched_barrier(0);
        __builtin_amdgcn_s_barrier();

        #pragma unroll 1
        for (int s = 0; s < 16; ++s) {
            const int slot = s & 3;
            if (s <= 12) TST((s + 3) & 3, (s + 3) * 128);   // WAR ok: read in step s-1
            const char* aB = Aflat + slot * 16384 + (wm3 * 32 + lr) * 128;
            const char* bB = Bflat + slot * 8192 + (wn3 * 32 + lr) * 128;
            bf16x8 a0f[2], a1f[2], b0f[2], b1f[2];
            #pragma unroll
            for (int m_ = 0; m_ < 2; ++m_) {
                a0f[m_] = *(const bf16x8*)(aB + m_ * 2048 + su0);
                a1f[m_] = *(const bf16x8*)(aB + m_ * 2048 + su1);
            }
            #pragma unroll
            for (int n_ = 0; n_ < 2; ++n_) {
                b0f[n_] = *(const bf16x8*)(bB + n_ * 2048 + su0);
                b1f[n_] = *(const bf16x8*)(bB + n_ * 2048 + su1);
            }
            asm volatile("s_waitcnt lgkmcnt(0)");
            __builtin_amdgcn_sched_barrier(0);
            __builtin_amdgcn_s_setprio(1);
            #pragma unroll
            for (int m_ = 0; m_ < 2; ++m_) {
                #pragma unroll
                for (int n_ = 0; n_ < 2; ++n_) {
                    acc[m_][n_] = __builtin_amdgcn_mfma_f32_16x16x32_bf16(
                        a0f[m_], b0f[n_], acc[m_][n_], 0, 0, 0);
                    acc[m_][n_] = __builtin_amdgcn_mfma_f32_16x16x32_bf16(
                        a1f[m_], b1f[n_], acc[m_][n_], 0, 0, 0);
                }
            }
            __builtin_amdgcn_s_setprio(0);
            // counted wait: keep 2 K-tiles in flight; drain the tile needed next.
            if (s <= 12)      asm volatile("s_waitcnt vmcnt(6)" ::: "memory");
            else if (s == 13) asm volatile("s_waitcnt vmcnt(3)" ::: "memory");
            else              asm volatile("s_waitcnt vmcnt(0)" ::: "memory");
            __builtin_amdgcn_sched_barrier(0);
            __builtin_amdgcn_s_barrier();
        }

        // epilogue (always off-diagonal, gi != gj guaranteed)
        int lc[2];
        lc[0] = labels[colStart + wn3 * 32 + lr];
        lc[1] = labels[colStart + wn3 * 32 + 16 + lr];
        float colAll[2] = {0.f, 0.f}, colPos[2] = {0.f, 0.f};
        #pragma unroll
        for (int m = 0; m < 2; ++m) {
            #pragma unroll
            for (int e = 0; e < 4; ++e) {
                const int gi = rowStart + wm3 * 32 + m * 16 + q * 4 + e;
                const int li = labels[gi];
                float s_all = 0.f, s_pos = 0.f;
                #pragma unroll
                for (int n = 0; n < 2; ++n) {
                    const float v = __expf(acc[m][n][e] * invT);
                    const bool same = (lc[n] == li);
                    s_all += v;
                    if (same) s_pos += v;
                    colAll[n] += v;
                    if (same) colPos[n] += v;
                }
                #pragma unroll
                for (int off = 1; off < 16; off <<= 1) {
                    s_all += __shfl_xor(s_all, off, 64);
                    s_pos += __shfl_xor(s_pos, off, 64);
                }
                if (lr == 0) {
                    atomicAdd(&sumExp[gi], s_all);
                    atomicAdd(&posSum[gi], s_pos);
                }
            }
        }
        #pragma unroll
        for (int n = 0; n < 2; ++n) {
            float a = colAll[n], pp = colPos[n];
            a += __shfl_xor(a, 16, 64);  a += __shfl_xor(a, 32, 64);
            pp += __shfl_xor(pp, 16, 64); pp += __shfl_xor(pp, 32, 64);
            if (q == 0) {
                const int gj = colStart + wn3 * 32 + n * 16 + lr;
                atomicAdd(&sumExp[gj], a);
                atomicAdd(&posSum[gj], pp);
            }
        }
        return;
    }

    // =======================================================================
    // FULL PATH: R2's verified 256^2 / BK=64 / 8-phase kernel, unchanged.
    // =======================================================================
    const int f0 = (int)blockIdx.x;
    const int f  = (f0 & 7) * (NFULL / 8) + (f0 >> 3);     // XCD swizzle, 512%8==0
    const int b  = (f < 496) ? f : f + 16;                 // skip split tiles

    int ti = (int)((sqrtf(8.0f * (float)b + 1.0f) - 1.0f) * 0.5f);
    while ((ti + 1) * (ti + 2) / 2 <= b) ++ti;
    while (ti * (ti + 1) / 2 > b) --ti;
    const int tj = b - ti * (ti + 1) / 2;
    const bool isDiag = (ti == tj);

    const int wm   = wave >> 2;     // 0..1 : row half
    const int wn   = wave & 3;      // 0..3 : 64-col strip
    const int rowStart = ti * BM;
    const int colStart = tj * BM;

    f32x4 acc[8][4];
    #pragma unroll
    for (int m = 0; m < 8; ++m)
        #pragma unroll
        for (int n = 0; n < 4; ++n) acc[m][n] = {0.f, 0.f, 0.f, 0.f};

    const int r0  = tid >> 3;                    // 0..63 (second load adds 64 rows)
    const int lu0 = (tid & 7) ^ (r0 & 7);
    const char* gA = (const char*)(E + (size_t)rowStart * D) + (size_t)r0 * (D * 2) + lu0 * 16;
    const char* gB = (const char*)(E + (size_t)colStart * D) + (size_t)r0 * (D * 2) + lu0 * 16;

    #define STAGE_A(buf, h, kb) do {                                                     \
        const char* g0_ = gA + (size_t)(h) * (128 * 2048) + (kb);                        \
        char* l0_ = (char*)&As[buf][h][0] + wave * 1024;                                 \
        __builtin_amdgcn_global_load_lds((const __attribute__((address_space(1))) void*)g0_, \
            (__attribute__((address_space(3))) void*)l0_, 16, 0, 0);                     \
        __builtin_amdgcn_global_load_lds(                                                \
            (const __attribute__((address_space(1))) void*)(g0_ + 64 * 2048),            \
            (__attribute__((address_space(3))) void*)(l0_ + 8192), 16, 0, 0);            \
    } while (0)
    #define STAGE_B(buf, h, kb) do {                                                     \
        const char* g0_ = gB + (size_t)(h) * (128 * 2048) + (kb);                        \
        char* l0_ = (char*)&Bs[buf][h][0] + wave * 1024;                                 \
        __builtin_amdgcn_global_load_lds((const __attribute__((address_space(1))) void*)g0_, \
            (__attribute__((address_space(3))) void*)l0_, 16, 0, 0);                     \
        __builtin_amdgcn_global_load_lds(                                                \
            (const __attribute__((address_space(1))) void*)(g0_ + 64 * 2048),            \
            (__attribute__((address_space(3))) void*)(l0_ + 8192), 16, 0, 0);            \
    } while (0)

    const char* rA0 = (const char*)&As[0][wm][0] + lr * 128;
    const char* rA1 = (const char*)&As[1][wm][0] + lr * 128;
    const char* rB0 = (const char*)&Bs[0][wn >> 1][0] + (wn & 1) * 8192 + lr * 128;
    const char* rB1 = (const char*)&Bs[1][wn >> 1][0] + (wn & 1) * 8192 + lr * 128;

    #define LD_A4(DST, RBASE, MOFFB, SU) do {                                            \
        _Pragma("unroll")                                                                \
        for (int m_ = 0; m_ < 4; ++m_)                                                   \
            DST[m_] = *(const bf16x8*)((RBASE) + (MOFFB) + m_ * 2048 + (SU));            \
    } while (0)
    #define LD_B4(DST, RBASE, SU) do {                                                   \
        _Pragma("unroll")                                                                \
        for (int n_ = 0; n_ < 4; ++n_)                                                   \
            DST[n_] = *(const bf16x8*)((RBASE) + n_ * 2048 + (SU));                      \
    } while (0)
    #define MFMA_QUAD(AF, BF, MO) do {                                                   \
        _Pragma("unroll")                                                                \
        for (int m_ = 0; m_ < 4; ++m_) {                                                 \
            _Pragma("unroll")                                                            \
            for (int n_ = 0; n_ < 4; ++n_)                                               \
                acc[(MO) + m_][n_] = __builtin_amdgcn_mfma_f32_16x16x32_bf16(            \
                    AF[m_], BF[n_], acc[(MO) + m_][n_], 0, 0, 0);                        \
        }                                                                                \
    } while (0)

    bf16x8 a0[4], a1[4], bq0[4], bq1[4];

    STAGE_B(0, 0, 0);  STAGE_B(0, 1, 0);
    STAGE_A(0, 0, 0);  STAGE_A(0, 1, 0);
    STAGE_B(1, 0, 128); STAGE_B(1, 1, 128);
    asm volatile("s_waitcnt vmcnt(4)" ::: "memory");
    __builtin_amdgcn_sched_barrier(0);
    __builtin_amdgcn_s_barrier();

    #pragma unroll 1
    for (int it = 0; it < ITERS; ++it) {
        const bool lastIt = (it == ITERS - 1);
        const int kb1 = (2 * it + 1) * 128;
        const int kb2 = (2 * it + 2) * 128;
        const int kb3 = (2 * it + 3) * 128;

        LD_A4(a0, rA0, 0, su0);
        LD_B4(bq0, rB0, su0);
        STAGE_A(1, 0, kb1);
        PHASE_MID();
        MFMA_QUAD(a0, bq0, 0);
        PHASE_END();

        LD_A4(a1, rA0, 0, su1);
        LD_B4(bq1, rB0, su1);
        STAGE_A(1, 1, kb1);
        PHASE_MID();
        MFMA_QUAD(a1, bq1, 0);
        PHASE_END();

        LD_A4(a0, rA0, 8192, su0);
        if (!lastIt) STAGE_B(0, 0, kb2);
        PHASE_MID();
        MFMA_QUAD(a0, bq0, 4);
        PHASE_END();

        LD_A4(a1, rA0, 8192, su1);
        if (!lastIt) {
            STAGE_B(0, 1, kb2);
            asm volatile("s_waitcnt vmcnt(4)" ::: "memory");
        } else {
            asm volatile("s_waitcnt vmcnt(0)" ::: "memory");
        }
        __builtin_amdgcn_sched_barrier(0);
        PHASE_MID();
        MFMA_QUAD(a1, bq1, 4);
        PHASE_END();

        LD_A4(a0, rA1, 0, su0);
        LD_B4(bq0, rB1, su0);
        if (!lastIt) STAGE_A(0, 0, kb2);
        PHASE_MID();
        MFMA_QUAD(a0, bq0, 0);
        PHASE_END();

        LD_A4(a1, rA1, 0, su1);
        LD_B4(bq1, rB1, su1);
        if (!lastIt) STAGE_A(0, 1, kb2);
        PHASE_MID();
        MFMA_QUAD(a1, bq1, 0);
        PHASE_END();

        LD_A4(a0, rA1, 8192, su0);
        if (!lastIt) STAGE_B(1, 0, kb3);
        PHASE_MID();
        MFMA_QUAD(a0, bq0, 4);
        PHASE_END();

        LD_A4(a1, rA1, 8192, su1);
        if (!lastIt) {
            STAGE_B(1, 1, kb3);
            asm volatile("s_waitcnt vmcnt(4)" ::: "memory");
            __builtin_amdgcn_sched_barrier(0);
        }
        PHASE_MID();
        MFMA_QUAD(a1, bq1, 4);
        PHASE_END();
    }

    int lc[4];
    #pragma unroll
    for (int n = 0; n < 4; ++n)
        lc[n] = labels[colStart + wn * 64 + n * 16 + lr];

    float colAll[4] = {0.f, 0.f, 0.f, 0.f};
    float colPos[4] = {0.f, 0.f, 0.f, 0.f};
    #pragma unroll
    for (int m = 0; m < 8; ++m) {
        #pragma unroll
        for (int e = 0; e < 4; ++e) {
            const int rloc = wm * 128 + m * 16 + q * 4 + e;
            const int gi   = rowStart + rloc;
            const int li   = labels[gi];
            float s_all = 0.f, s_pos = 0.f;
            #pragma unroll
            for (int n = 0; n < 4; ++n) {
                const int cloc = wn * 64 + n * 16 + lr;
                const int gj   = colStart + cloc;
                const float v  = __expf(acc[m][n][e] * invT);
                const bool same = (lc[n] == li);
                s_all += v;
                if (same && gi != gj) s_pos += v;
                if (!isDiag) {
                    colAll[n] += v;
                    if (same) colPos[n] += v;
                }
            }
            #pragma unroll
            for (int off = 1; off < 16; off <<= 1) {
                s_all += __shfl_xor(s_all, off, 64);
                s_pos += __shfl_xor(s_pos, off, 64);
            }
            if (lr == 0) {
                atomicAdd(&sumExp[gi], s_all);
                atomicAdd(&posSum[gi], s_pos);
            }
        }
    }
    if (!isDiag) {
        #pragma unroll
        for (int n = 0; n < 4; ++n) {
            float a = colAll[n], p = colPos[n];
            a += __shfl_xor(a, 16, 64);  a += __shfl_xor(a, 32, 64);
            p += __shfl_xor(p, 16, 64);  p += __shfl_xor(p, 32, 64);
            if (q == 0) {
                const int gj = colStart + wn * 64 + n * 16 + lr;
                atomicAdd(&sumExp[gj], a);
                atomicAdd(&posSum[gj], p);
            }
        }
    }
}

// ---------------------------------------------------------------------------
// Kernel 3: loss_i = log(sumExp_i / posSum_i); out = mean(loss).
// ---------------------------------------------------------------------------
__global__ __launch_bounds__(1024) void finalize(const float* __restrict__ sumExp,
                                                 const float* __restrict__ posSum,
                                                 float* __restrict__ out) {
    const int tid = threadIdx.x;
    float s = 0.f;
    #pragma unroll
    for (int i = tid; i < N; i += 1024)
        s += __logf(sumExp[i] / posSum[i]);
    #pragma unroll
    for (int off = 32; off >= 1; off >>= 1) s += __shfl_xor(s, off, 64);
    __shared__ float red[16];
    if ((tid & 63) == 0) red[tid >> 6] = s;
    __syncthreads();
    if (tid == 0) {
        float t = 0.f;
        #pragma unroll
        for (int i = 0; i < 16; ++i) t += red[i];
        out[0] = t / (float)N;
    }
}

extern "C" void kernel_launch(void* const* d_in, const int* in_sizes, int n_in,
                              void* d_out, int out_size, void* d_ws, size_t ws_size,
                              hipStream_t stream) {
    const float* emb    = (const float*)d_in[0];
    const int*   labels = (const int*)d_in[1];
    float* out = (float*)d_out;

    // ws layout: [sumExp: N floats][posSum: N floats][EN: N*D bf16]
    float*  sumExp = (float*)d_ws;
    float*  posSum = sumExp + N;
    bf16_t* EN     = (bf16_t*)((char*)d_ws + (size_t)2 * N * sizeof(float));

    norm_cast<<<N / 4, 256, 0, stream>>>(emb, EN, sumExp, posSum);

    gemm_fused<<<NBLK, 512, 0, stream>>>(EN, labels, sumExp, posSum);

    finalize<<<1, 1024, 0, stream>>>(sumExp, posSum, out);
}